// Round 1
// baseline (1142.907 us; speedup 1.0000x reference)
//
#include <hip/hip_runtime.h>
#include <math.h>

namespace {

constexpr int H = 64;
constexpr int C = 32;
constexpr int L = 16;
constexpr int T = 32;
constexpr int MAXI = L + T;   // 48
constexpr int NB = 32;        // one block per candidate edge
constexpr int NT = 256;

__device__ __forceinline__ float gelu_exact(float v) {
  // jax.nn.gelu(approximate=False): v * 0.5 * (1 + erf(v/sqrt(2)))
  double d = (double)v;
  return (float)(0.5 * d * (1.0 + erf(d * 0.70710678118654752440)));
}

// One-shot per-slot grid barrier. Slots zeroed by hipMemsetAsync before launch.
// __syncthreads() before arrival drains all lanes' agent-scope stores
// (s_waitcnt vmcnt(0) precedes s_barrier), so thread 0's release-add publishes
// the whole block's data.
__device__ __forceinline__ void grid_barrier(int* cnt, int slot) {
  __syncthreads();
  if (threadIdx.x == 0) {
    __hip_atomic_fetch_add(&cnt[slot], 1, __ATOMIC_RELEASE, __HIP_MEMORY_SCOPE_AGENT);
    while (__hip_atomic_load(&cnt[slot], __ATOMIC_ACQUIRE, __HIP_MEMORY_SCOPE_AGENT) < NB) {
      __builtin_amdgcn_s_sleep(2);
    }
  }
  __syncthreads();
}

__global__ __launch_bounds__(NT) void bralm_kernel(
    const float* __restrict__ W,     // (E,H,H)
    const float* __restrict__ Bv,    // (E,1,H)
    const float* __restrict__ pos,   // (512,1)
    const int* __restrict__ sedge,   // (L,)
    const int* __restrict__ nedge,   // (N,C)
    const int* __restrict__ nnode,   // (N,C)
    const int* __restrict__ x0p,     // (1,)
    float* __restrict__ out,         // 48*64 cache then 32 tokens (as f32)
    int* __restrict__ bar,           // 64 ints (one-shot barrier slots)
    float* __restrict__ wsen,        // [2][C] energies
    float* __restrict__ wsnx)        // [2][C][H] candidate rows
{
  const int tid = (int)threadIdx.x;
  const int lane = tid & 63;
  const int wv = tid >> 6;
  const int c = (int)blockIdx.x;

  __shared__ float s_pe[T][H];      // pe rows 0..31 (max index used is 31)
  __shared__ float s_cache[MAXI][H];
  __shared__ float s_wts[H];
  __shared__ float s_e[H];
  __shared__ float s_part[4][H];
  __shared__ int s_ce;
  __shared__ int s_idx;
  __shared__ int s_x;

  // ---- positional encoding: div_term = 10000^(j/32) rounded double->f32,
  //      arg = f32(i) * dt in f32, sin/cos in double on the f32 argument.
  for (int idx = tid; idx < T * H; idx += NT) {
    int i = idx >> 6, k = idx & 63, j = k >> 1;
    float dtf = (float)pow(10000.0, (double)j / 32.0);
    float arg = (float)i * dtf;
    s_pe[i][k] = (k & 1) ? (float)cos((double)arg) : (float)sin((double)arg);
  }
  if (tid < H) s_e[tid] = 1.0f / (float)H;   // e0 = ones/H
  __syncthreads();

  // ---- prompt: executed redundantly by every block (deterministic, no sync)
  for (int i = 0; i < L; ++i) {
    if (i > 0) {
      if (wv == 0) {
        float p = (lane < i) ? pos[lane] : -INFINITY;
        float m = p;
        #pragma unroll
        for (int off = 32; off; off >>= 1) m = fmaxf(m, __shfl_down(m, off));
        m = __shfl(m, 0);
        float ex = (lane < i) ? expf(p - m) : 0.0f;
        float s = ex;
        #pragma unroll
        for (int off = 32; off; off >>= 1) s += __shfl_down(s, off);
        s = __shfl(s, 0);
        s_wts[lane] = ex / s;
      }
      __syncthreads();
      if (wv == 0) {
        float acc = 0.0f;
        for (int j = 0; j < i; ++j) acc = fmaf(s_wts[j], s_cache[j][lane], acc);
        s_e[lane] = acc;
      }
      __syncthreads();
    }
    const int e = sedge[i];
    const float* Wr = W + (long long)e * (H * H);
    float acc = 0.0f;
    const int h0 = wv * 16;
    #pragma unroll
    for (int hh = 0; hh < 16; ++hh)
      acc = fmaf(s_e[h0 + hh], Wr[(h0 + hh) * H + lane], acc);
    s_part[wv][lane] = acc;
    __syncthreads();
    if (wv == 0) {
      float v = ((s_part[0][lane] + s_part[1][lane]) + s_part[2][lane]) + s_part[3][lane];
      v += Bv[(long long)e * H + lane] + s_pe[i][lane];
      s_cache[i][lane] = gelu_exact(v);
    }
    __syncthreads();
  }

  // ---- generation: block c owns candidate edge c each step
  int x = x0p[0];
  for (int t = 0; t < T; ++t) {
    const int curr_i = L + t;
    const int p = t & 1;
    if (wv == 0) {
      float pv = (lane < curr_i) ? pos[lane] : -INFINITY;
      float m = pv;
      #pragma unroll
      for (int off = 32; off; off >>= 1) m = fmaxf(m, __shfl_down(m, off));
      m = __shfl(m, 0);
      float ex = (lane < curr_i) ? expf(pv - m) : 0.0f;
      float s = ex;
      #pragma unroll
      for (int off = 32; off; off >>= 1) s += __shfl_down(s, off);
      s = __shfl(s, 0);
      s_wts[lane] = ex / s;
    }
    if (tid == NT - 1) s_ce = nedge[x * C + c];
    __syncthreads();
    if (wv == 0) {
      float acc = 0.0f;
      for (int j = 0; j < curr_i; ++j) acc = fmaf(s_wts[j], s_cache[j][lane], acc);
      s_e[lane] = acc;
    }
    __syncthreads();
    const int ce = s_ce;
    const float* Wr = W + (long long)ce * (H * H);
    float acc = 0.0f;
    const int h0 = wv * 16;
    #pragma unroll
    for (int hh = 0; hh < 16; ++hh)
      acc = fmaf(s_e[h0 + hh], Wr[(h0 + hh) * H + lane], acc);
    s_part[wv][lane] = acc;
    __syncthreads();
    if (wv == 0) {
      float v = ((s_part[0][lane] + s_part[1][lane]) + s_part[2][lane]) + s_part[3][lane];
      v += Bv[(long long)ce * H + lane] + s_pe[t][lane];
      v = gelu_exact(v);
      __hip_atomic_store(&wsnx[(p * C + c) * H + lane], v,
                         __ATOMIC_RELAXED, __HIP_MEMORY_SCOPE_AGENT);
      float sq = v * v;
      #pragma unroll
      for (int off = 32; off; off >>= 1) sq += __shfl_down(sq, off);
      if (lane == 0)
        __hip_atomic_store(&wsen[p * C + c], sqrtf(sq),
                           __ATOMIC_RELAXED, __HIP_MEMORY_SCOPE_AGENT);
    }
    grid_barrier(bar, t);
    // every block redundantly selects the winner (first max => min index on ties)
    if (wv == 0) {
      float en = (lane < C)
        ? __hip_atomic_load(&wsen[p * C + lane], __ATOMIC_RELAXED, __HIP_MEMORY_SCOPE_AGENT)
        : -INFINITY;
      int bi = lane;
      #pragma unroll
      for (int off = 32; off; off >>= 1) {
        float oe = __shfl_down(en, off);
        int ob = __shfl_down(bi, off);
        if (oe > en || (oe == en && ob < bi)) { en = oe; bi = ob; }
      }
      bi = __shfl(bi, 0);
      if (lane == 0) { s_idx = bi; s_x = nnode[x * C + bi]; }
    }
    __syncthreads();
    const int idx = s_idx;
    if (wv == 0) {
      s_cache[curr_i][lane] = __hip_atomic_load(&wsnx[(p * C + idx) * H + lane],
                                                __ATOMIC_RELAXED, __HIP_MEMORY_SCOPE_AGENT);
    }
    if (c == 0 && tid == NT - 1) out[MAXI * H + t] = (float)s_x;
    x = s_x;
    __syncthreads();
  }

  // ---- block 0 writes the full cache
  if (c == 0) {
    for (int idx = tid; idx < MAXI * H; idx += NT)
      out[idx] = s_cache[idx >> 6][idx & 63];
  }
}

} // namespace

extern "C" void kernel_launch(void* const* d_in, const int* in_sizes, int n_in,
                              void* d_out, int out_size, void* d_ws, size_t ws_size,
                              hipStream_t stream) {
  const float* W   = (const float*)d_in[0];
  const float* Bv  = (const float*)d_in[1];
  const float* pos = (const float*)d_in[2];
  const int* se    = (const int*)d_in[3];
  const int* ne    = (const int*)d_in[4];
  const int* nn    = (const int*)d_in[5];
  const int* x0    = (const int*)d_in[6];
  float* out = (float*)d_out;

  int*   bar  = (int*)d_ws;                      // 64 ints, one-shot barrier slots
  float* wsen = (float*)((char*)d_ws + 256);     // [2][32] energies
  float* wsnx = (float*)((char*)d_ws + 512);     // [2][32][64] candidate rows

  // zero the barrier slots (d_ws is poisoned to 0xAA before every call)
  hipMemsetAsync(d_ws, 0, 256, stream);

  void* args[] = {&W, &Bv, &pos, &se, &ne, &nn, &x0, &out, &bar, &wsen, &wsnx};
  hipLaunchCooperativeKernel((const void*)bralm_kernel, dim3(NB), dim3(NT),
                             args, 0, stream);
}